// Round 3
// baseline (320.832 us; speedup 1.0000x reference)
//
#include <hip/hip_runtime.h>

#define XDIM 512
#define CDIM 32
#define NPIX (XDIM * XDIM)
#define NB 8

typedef short bf16x8 __attribute__((ext_vector_type(8)));
typedef float f32x4 __attribute__((ext_vector_type(4)));
typedef float f32x16 __attribute__((ext_vector_type(16)));

#define FEATS_BYTES (NPIX * CDIM * 4)   // 33.5 MB

__device__ __forceinline__ short f2bf(float v) {
    __bf16 b = (__bf16)v;
    return __builtin_bit_cast(short, b);
}
__device__ __forceinline__ float bfup(short s) {
    return (float)__builtin_bit_cast(__bf16, s);
}

// ---------------------------------------------------------------------------
// Weight prep for 32x32x16 MFMA, hi/lo bf16 split, sigma k-relabeling:
// hardware k-slot (T, h, j) holds logical channel c = 16T + 4h + (j&3) + 8*(j>>2).
// This makes the D-register channel residency ((reg&3)+8*(reg>>2)+4h) exactly
// the next layer's B-fragment order -> zero cross-lane repack between layers.
// A-frag: lane l holds row m = l&31, slots j=0..7 of half h = l>>5.
// ---------------------------------------------------------------------------
__global__ __launch_bounds__(64) void wprep_kernel(
    const float* __restrict__ w_h, const float* __restrict__ r_wh,
    unsigned short* __restrict__ afrag)
{
    int L = blockIdx.x >> 1;      // 0..5
    int T = blockIdx.x & 1;       // K-tile
    int l = threadIdx.x;
    const float* W = (L < 3) ? (w_h + L * CDIM * CDIM) : (r_wh + (L - 3) * CDIM * CDIM);
    int m = l & 31;
    int h = l >> 5;
    unsigned short* dh = afrag + (((L * 2 + T) * 2 + 0) * 64 + l) * 8;
    unsigned short* dl = afrag + (((L * 2 + T) * 2 + 1) * 64 + l) * 8;
    for (int j = 0; j < 8; j++) {
        int c = 16 * T + 4 * h + (j & 3) + 8 * (j >> 2);
        float v = W[c * CDIM + m];          // A[m][k] = W[k][m]
        short hi = f2bf(v);
        short lo = f2bf(v - bfup(hi));
        dh[j] = (unsigned short)hi;
        dl[j] = (unsigned short)lo;
    }
}

// ---------------------------------------------------------------------------
// Batch-independent bilinear feature image (unchanged).
// ---------------------------------------------------------------------------
__global__ __launch_bounds__(256) void feats_kernel(
    const float* __restrict__ data, const float* __restrict__ lerp_w,
    const int* __restrict__ x0, const int* __restrict__ y0,
    const int* __restrict__ x1, const int* __restrict__ y1,
    float* __restrict__ feats)
{
    int tid = blockIdx.x * 256 + threadIdx.x;
    int p = tid >> 5;
    int c = tid & 31;
    if (p >= NPIX) return;
    float wA = lerp_w[p * 2 + 0];
    float wB = lerp_w[p * 2 + 1];
    int xa = x0[p], ya = y0[p], xb = x1[p], yb = y1[p];
    float v00 = data[(ya * XDIM + xa) * CDIM + c];
    float v01 = data[(ya * XDIM + xb) * CDIM + c];
    float v10 = data[(yb * XDIM + xa) * CDIM + c];
    float v11 = data[(yb * XDIM + xb) * CDIM + c];
    float r = v00 * (1.f - wA) * (1.f - wB) + v01 * wA * (1.f - wB)
            + v10 * (1.f - wA) * wB + v11 * wA * wB;
    feats[p * CDIM + c] = r;
}

// ---------------------------------------------------------------------------
// Fused kernel, 32x32x16 MFMA. One wave = 32 pixels of one batch.
// lane: p = lane&31 (pixel), h = lane>>5 (channel half).
// Activation state a[16]: a[r] = value of channel ch(r,h) = (r&3)+8*(r>>2)+4h
// of pixel p. B-frags = {a[0..7], a[8..15]} directly (sigma relabeling).
// ---------------------------------------------------------------------------
__device__ __forceinline__ void build2(const float a[16], bf16x8 bh[2], bf16x8 bl[2]) {
    #pragma unroll
    for (int r = 0; r < 16; r++) {
        short hi = f2bf(a[r]);
        bh[r >> 3][r & 7] = hi;
        bl[r >> 3][r & 7] = f2bf(a[r] - bfup(hi));
    }
}

__device__ __forceinline__ f32x16 matmul6(
    const unsigned short* __restrict__ afrag, int L, int lane,
    const bf16x8 bh[2], const bf16x8 bl[2])
{
    const bf16x8* ap = (const bf16x8*)afrag;
    f32x16 acc = {0.f, 0.f, 0.f, 0.f, 0.f, 0.f, 0.f, 0.f,
                  0.f, 0.f, 0.f, 0.f, 0.f, 0.f, 0.f, 0.f};
    #pragma unroll
    for (int T = 0; T < 2; T++) {
        bf16x8 ah = ap[((L * 2 + T) * 2 + 0) * 64 + lane];
        bf16x8 al = ap[((L * 2 + T) * 2 + 1) * 64 + lane];
        acc = __builtin_amdgcn_mfma_f32_32x32x16_bf16(al, bh[T], acc, 0, 0, 0);
        acc = __builtin_amdgcn_mfma_f32_32x32x16_bf16(ah, bl[T], acc, 0, 0, 0);
        acc = __builtin_amdgcn_mfma_f32_32x32x16_bf16(ah, bh[T], acc, 0, 0, 0);
    }
    return acc;
}

__global__ __launch_bounds__(256) void fused_mfma_kernel(
    const float* __restrict__ t, const float* __restrict__ xy_basis,
    const float* __restrict__ w_in, const float* __restrict__ b_in,
    const float* __restrict__ b_h,
    const float* __restrict__ ln_g, const float* __restrict__ ln_b,
    const float* __restrict__ w_out, const float* __restrict__ b_out,
    const float* __restrict__ r_bh,
    const float* __restrict__ r_wo, const float* __restrict__ r_bo,
    const float* __restrict__ feats, const unsigned short* __restrict__ afrag,
    float* __restrict__ out)
{
    int lane = threadIdx.x & 63;
    int p = lane & 31, h = lane >> 5;

    // XCD-chunked swizzle (nwg = 16384, 8 XCDs, 2048 blocks each) + batch-minor:
    // each XCD sweeps a contiguous 1/8 of the image across all 8 batches ->
    // its feats slice (~4.2 MB) stays L2-resident.
    int bid = blockIdx.x;
    int swz = (bid & 7) * 2048 + (bid >> 3);
    int gw = swz * 4 + (int)(threadIdx.x >> 6);
    int b = gw & 7;
    int pbase = (gw >> 3) << 5;
    int pix = pbase + p;

    float alpha = t[b] + 0.5f;
    float2 xy = ((const float2*)xy_basis)[pix];

    // ---- input layer: a[r] = h0[ch(r,h)] ----
    float a[16];
    #pragma unroll
    for (int g = 0; g < 4; g++) {
        int c = 8 * g + 4 * h;
        f32x4 w0 = *(const f32x4*)(w_in + c);
        f32x4 w1 = *(const f32x4*)(w_in + CDIM + c);
        f32x4 w2 = *(const f32x4*)(w_in + 2 * CDIM + c);
        f32x4 bb = *(const f32x4*)(b_in + c);
        #pragma unroll
        for (int i = 0; i < 4; i++)
            a[4 * g + i] = fmaf(xy.x, w0[i], fmaf(xy.y, w1[i], fmaf(alpha, w2[i], bb[i])));
    }

    // ---- 3 warp layers: sin(LN(h@W + b)) ----
    #pragma unroll 1
    for (int L = 0; L < 3; L++) {
        bf16x8 bh[2], bl[2];
        build2(a, bh, bl);
        f32x16 acc = matmul6(afrag, L, lane, bh, bl);

        float sum = 0.f, sq = 0.f;
        #pragma unroll
        for (int g = 0; g < 4; g++) {
            f32x4 bia = *(const f32x4*)(b_h + L * CDIM + 8 * g + 4 * h);
            #pragma unroll
            for (int i = 0; i < 4; i++) {
                float v = acc[4 * g + i] + bia[i];
                a[4 * g + i] = v;
                sum += v;
                sq = fmaf(v, v, sq);
            }
        }
        sum += __shfl_xor(sum, 32, 64);
        sq  += __shfl_xor(sq, 32, 64);
        float mu = sum * (1.f / 32.f);
        float var = fmaf(sq, 1.f / 32.f, -mu * mu);
        float rs = rsqrtf(var + 1e-5f);
        #pragma unroll
        for (int g = 0; g < 4; g++) {
            f32x4 gg = *(const f32x4*)(ln_g + L * CDIM + 8 * g + 4 * h);
            f32x4 be = *(const f32x4*)(ln_b + L * CDIM + 8 * g + 4 * h);
            #pragma unroll
            for (int i = 0; i < 4; i++)
                a[4 * g + i] = __sinf(fmaf((a[4 * g + i] - mu) * rs, gg[i], be[i]));
        }
    }

    // ---- motion head ----
    float mx = 0.f, my = 0.f;
    #pragma unroll
    for (int g = 0; g < 4; g++) {
        int c = 8 * g + 4 * h;
        f32x4 wa = *(const f32x4*)(w_out + 2 * c);       // rows c, c+1
        f32x4 wb = *(const f32x4*)(w_out + 2 * c + 4);   // rows c+2, c+3
        mx = fmaf(a[4 * g + 0], wa[0], mx); my = fmaf(a[4 * g + 0], wa[1], my);
        mx = fmaf(a[4 * g + 1], wa[2], mx); my = fmaf(a[4 * g + 1], wa[3], my);
        mx = fmaf(a[4 * g + 2], wb[0], mx); my = fmaf(a[4 * g + 2], wb[1], my);
        mx = fmaf(a[4 * g + 3], wb[2], mx); my = fmaf(a[4 * g + 3], wb[3], my);
    }
    mx += __shfl_xor(mx, 32, 64);
    my += __shfl_xor(my, 32, 64);
    float gridx = fmaf(mx + b_out[0], 0.1f, xy.x);
    float gridy = fmaf(my + b_out[1], 0.1f, xy.y);

    // ---- grid sample: channels ch(r,h) of pixel p ----
    float ix = ((gridx + 1.0f) * (float)XDIM - 1.0f) * 0.5f;
    float iy = ((gridy + 1.0f) * (float)XDIM - 1.0f) * 0.5f;
    float x0f = floorf(ix), y0f = floorf(iy);
    float wx = ix - x0f, wy = iy - y0f;
    #pragma unroll
    for (int r = 0; r < 16; r++) a[r] = 0.f;
    #pragma unroll
    for (int corner = 0; corner < 4; corner++) {
        float xf = x0f + (float)(corner & 1);
        float yf = y0f + (float)(corner >> 1);
        float w = ((corner & 1) ? wx : 1.f - wx) * ((corner >> 1) ? wy : 1.f - wy);
        bool valid = (xf >= 0.f) && (xf <= (float)(XDIM - 1)) &&
                     (yf >= 0.f) && (yf <= (float)(XDIM - 1));
        if (!valid) w = 0.f;
        int xi = (int)fminf(fmaxf(xf, 0.f), (float)(XDIM - 1));
        int yi = (int)fminf(fmaxf(yf, 0.f), (float)(XDIM - 1));
        const float* fp = feats + (yi * XDIM + xi) * CDIM + 4 * h;
        #pragma unroll
        for (int g = 0; g < 4; g++) {
            f32x4 v = *(const f32x4*)(fp + 8 * g);
            #pragma unroll
            for (int i = 0; i < 4; i++)
                a[4 * g + i] = fmaf(w, v[i], a[4 * g + i]);
        }
    }

    // ---- 3 render layers: relu(z@W + b) ----
    #pragma unroll 1
    for (int L = 3; L < 6; L++) {
        bf16x8 bh[2], bl[2];
        build2(a, bh, bl);
        f32x16 acc = matmul6(afrag, L, lane, bh, bl);
        #pragma unroll
        for (int g = 0; g < 4; g++) {
            f32x4 bia = *(const f32x4*)(r_bh + (L - 3) * CDIM + 8 * g + 4 * h);
            #pragma unroll
            for (int i = 0; i < 4; i++)
                a[4 * g + i] = fmaxf(acc[4 * g + i] + bia[i], 0.f);
        }
    }

    // ---- output head ----
    float o = 0.f;
    #pragma unroll
    for (int g = 0; g < 4; g++) {
        f32x4 wz = *(const f32x4*)(r_wo + 8 * g + 4 * h);
        #pragma unroll
        for (int i = 0; i < 4; i++) o = fmaf(a[4 * g + i], wz[i], o);
    }
    o += __shfl_xor(o, 32, 64);
    o += r_bo[0];
    o = (o >= 0.f) ? o : 0.001f * o;
    if (h == 0) out[b * NPIX + pix] = o;
}

extern "C" void kernel_launch(void* const* d_in, const int* in_sizes, int n_in,
                              void* d_out, int out_size, void* d_ws, size_t ws_size,
                              hipStream_t stream) {
    const float* t        = (const float*)d_in[0];
    const float* data     = (const float*)d_in[1];
    const float* lerp_w   = (const float*)d_in[2];
    const float* xy_basis = (const float*)d_in[3];
    const float* w_in     = (const float*)d_in[4];
    const float* b_in     = (const float*)d_in[5];
    const float* w_h      = (const float*)d_in[6];
    const float* b_h      = (const float*)d_in[7];
    const float* ln_g     = (const float*)d_in[8];
    const float* ln_b     = (const float*)d_in[9];
    const float* w_out    = (const float*)d_in[10];
    const float* b_out    = (const float*)d_in[11];
    const float* r_wh     = (const float*)d_in[12];
    const float* r_bh     = (const float*)d_in[13];
    const float* r_wo     = (const float*)d_in[14];
    const float* r_bo     = (const float*)d_in[15];
    const int* x0 = (const int*)d_in[16];
    const int* y0 = (const int*)d_in[17];
    const int* x1 = (const int*)d_in[18];
    const int* y1 = (const int*)d_in[19];

    float* feats = (float*)d_ws;
    unsigned short* afrag = (unsigned short*)((char*)d_ws + FEATS_BYTES);
    float* out = (float*)d_out;

    wprep_kernel<<<12, 64, 0, stream>>>(w_h, r_wh, afrag);
    feats_kernel<<<(NPIX * CDIM) / 256, 256, 0, stream>>>(data, lerp_w, x0, y0, x1, y1, feats);
    fused_mfma_kernel<<<(NB * NPIX) / 128, 256, 0, stream>>>(
        t, xy_basis, w_in, b_in, b_h, ln_g, ln_b, w_out, b_out,
        r_bh, r_wo, r_bo, feats, afrag, out);
}